// Round 1
// baseline (1152.993 us; speedup 1.0000x reference)
//
#include <hip/hip_runtime.h>
#include <stdint.h>

// ---------- types ----------
typedef __attribute__((ext_vector_type(4))) float f32x4;
typedef __attribute__((ext_vector_type(8))) short bf16x8;

__device__ __forceinline__ short f2bf(float x) {
  unsigned int u = __builtin_bit_cast(unsigned int, x);
  unsigned int r = (u + 0x7fffu + ((u >> 16) & 1u)) >> 16;
  return (short)r;
}
__device__ __forceinline__ float bf2f(short s) {
  unsigned int u = ((unsigned int)(unsigned short)s) << 16;
  return __builtin_bit_cast(float, u);
}

__device__ __forceinline__ void gload_lds16(const void* g, void* l) {
  __builtin_amdgcn_global_load_lds(
      (const __attribute__((address_space(1))) void*)g,
      (__attribute__((address_space(3))) void*)l, 16, 0, 0);
}

// ---------- K0: fp32 -> bf16 convert ----------
__global__ __launch_bounds__(256) void cvt_bf16(const float* __restrict__ in,
                                                short* __restrict__ out, int n) {
  int idx = blockIdx.x * blockDim.x + threadIdx.x;
  int stride = gridDim.x * blockDim.x;
  for (int i = idx * 4; i < n; i += stride * 4) {
    float4 v = *(const float4*)(in + i);
    short4 o;
    o.x = f2bf(v.x); o.y = f2bf(v.y); o.z = f2bf(v.z); o.w = f2bf(v.w);
    *(short4*)(out + i) = o;
  }
}

// ---------- RoPE table: tab[s][j] = (cos, sin)(s * 10000^(-j/64)), s<2048, j<64 ----------
__global__ __launch_bounds__(256) void rope_table_k(float2* __restrict__ tab) {
  int idx = blockIdx.x * 256 + threadIdx.x;  // 131072 total
  int s = idx >> 6, j = idx & 63;
  float invf = powf(10000.0f, -((float)j) / 64.0f);
  float a = (float)s * invf;
  tab[idx] = make_float2(cosf(a), sinf(a));
}

// ---------- RoPE apply in-place on Q and K (token-major [4096][4096] bf16) ----------
__global__ __launch_bounds__(256) void rope_apply_k(short* __restrict__ Qb,
                                                    short* __restrict__ Kb,
                                                    const float2* __restrict__ tab) {
  short* base = blockIdx.y ? Kb : Qb;
  int token = blockIdx.x;
  int s = token & 2047;
  short* rowp = base + (size_t)token * 4096;
  const float2* trow = tab + s * 64;
  for (int u = threadIdx.x; u < 512; u += 256) {
    int h = u >> 4;
    int d0 = (u & 15) * 4;
    short* p1 = rowp + h * 128 + d0;
    short* p2 = p1 + 64;
    short4 a = *(short4*)p1, b = *(short4*)p2;
    short4 ra, rb;
#pragma unroll
    for (int j = 0; j < 4; ++j) {
      short aj = (&a.x)[j], bj = (&b.x)[j];
      float qa = bf2f(aj), qb = bf2f(bj);
      float2 cs = trow[d0 + j];
      (&ra.x)[j] = f2bf(qa * cs.x - qb * cs.y);
      (&rb.x)[j] = f2bf(qb * cs.x + qa * cs.y);
    }
    *(short4*)p1 = ra;
    *(short4*)p2 = rb;
  }
}

// ---------- GEMM: C[4096][4096] = A * B^T, bf16 in, fp32 acc ----------
// MODE 0: bf16 row-major out. MODE 1: fp32 row-major out. MODE 2: Vt out [bh][d][s] bf16.
template <int MODE>
__global__ __launch_bounds__(256) void gemm128(const short* __restrict__ A,
                                               const short* __restrict__ Bw,
                                               void* __restrict__ out) {
  __shared__ __attribute__((aligned(16))) short lA[128 * 64];
  __shared__ __attribute__((aligned(16))) short lB[128 * 64];
  int wg = blockIdx.x;                      // 1024 blocks
  int swz = (wg & 7) * 128 + (wg >> 3);     // XCD swizzle (1024 % 8 == 0, bijective)
  int by = swz >> 5;                        // m-tile 0..31
  int bx = swz & 31;                        // n-tile 0..31
  int tid = threadIdx.x;
  int w = tid >> 6, lane = tid & 63;
  int l16 = lane & 15, l4 = lane >> 4;
  int wr = w >> 1, wc = w & 1;

  f32x4 acc[4][4] = {};

  int srow = lane >> 3;  // 8 rows (128B each) per 1KB segment
  int skb = lane & 7;

  for (int kt = 0; kt < 64; ++kt) {
#pragma unroll
    for (int ii = 0; ii < 4; ++ii) {
      int s = w * 4 + ii;
      int row = s * 8 + srow;
      int src = skb ^ (row & 7);  // pre-swizzled global source, linear LDS dest
      gload_lds16(A + (size_t)(by * 128 + row) * 4096 + kt * 64 + src * 8, &lA[s * 512]);
      gload_lds16(Bw + (size_t)(bx * 128 + row) * 4096 + kt * 64 + src * 8, &lB[s * 512]);
    }
    __syncthreads();  // vmcnt(0) drained by barrier: staged tile visible
#pragma unroll
    for (int kk = 0; kk < 2; ++kk) {
      bf16x8 af[4], bfr[4];
#pragma unroll
      for (int m4 = 0; m4 < 4; ++m4) {
        int row = wr * 64 + m4 * 16 + l16;
        int phys = (kk * 4 + l4) ^ (row & 7);
        af[m4] = *(const bf16x8*)&lA[row * 64 + phys * 8];
      }
#pragma unroll
      for (int n4 = 0; n4 < 4; ++n4) {
        int row = wc * 64 + n4 * 16 + l16;
        int phys = (kk * 4 + l4) ^ (row & 7);
        bfr[n4] = *(const bf16x8*)&lB[row * 64 + phys * 8];
      }
#pragma unroll
      for (int m4 = 0; m4 < 4; ++m4)
#pragma unroll
        for (int n4 = 0; n4 < 4; ++n4)
          acc[m4][n4] = __builtin_amdgcn_mfma_f32_16x16x32_bf16(af[m4], bfr[n4], acc[m4][n4], 0, 0, 0);
    }
    __syncthreads();  // all reads done before next stage overwrites
  }

  int orow0 = by * 128 + wr * 64;
  int ocol0 = bx * 128 + wc * 64;
#pragma unroll
  for (int m4 = 0; m4 < 4; ++m4)
#pragma unroll
    for (int n4 = 0; n4 < 4; ++n4)
#pragma unroll
      for (int i = 0; i < 4; ++i) {
        int r = orow0 + m4 * 16 + l4 * 4 + i;
        int c = ocol0 + n4 * 16 + l16;
        float v = acc[m4][n4][i];
        if constexpr (MODE == 0) {
          ((short*)out)[(size_t)r * 4096 + c] = f2bf(v);
        } else if constexpr (MODE == 1) {
          ((float*)out)[(size_t)r * 4096 + c] = v;
        } else {
          int bb = r >> 11, ss = r & 2047;
          int h = c >> 7, d = c & 127;
          ((short*)out)[(((size_t)((bb * 32 + h) * 128 + d)) << 11) + ss] = f2bf(v);
        }
      }
}

// ---------- Flash attention: Q,K token-major [4096][4096], Vt [64][128][2048], out AO token-major ----------
__global__ __launch_bounds__(256) void attn_k(const short* __restrict__ Qb,
                                              const short* __restrict__ Kb,
                                              const short* __restrict__ Vt,
                                              short* __restrict__ AO) {
  __shared__ __attribute__((aligned(16))) short lK[64 * 128];
  __shared__ __attribute__((aligned(16))) short lV[128 * 64];
  __shared__ __attribute__((aligned(16))) short lP[4][16 * 72];  // padded rows (72) for bank spread
  int qt = blockIdx.x;   // 0..31 (64 q rows per block)
  int bh = blockIdx.y;   // 0..63
  int b = bh >> 5, h = bh & 31;
  int tid = threadIdx.x, w = tid >> 6, lane = tid & 63;
  int l16 = lane & 15, l4 = lane >> 4;

  // Q fragments in registers: wave w owns q rows [qt*64 + w*16, +16)
  const short* Qg = Qb + (size_t)(b * 2048 + qt * 64 + w * 16 + l16) * 4096 + h * 128 + l4 * 8;
  bf16x8 qf[4];
#pragma unroll
  for (int kk = 0; kk < 4; ++kk) qf[kk] = *(const bf16x8*)(Qg + kk * 32);

  f32x4 oacc[8] = {};
  float mrun[4], lsum[4];
#pragma unroll
  for (int i = 0; i < 4; ++i) { mrun[i] = -1e30f; lsum[i] = 0.f; }

  const short* Kbase = Kb + (size_t)(b * 2048) * 4096 + h * 128;
  const short* Vbase = Vt + (size_t)bh * 128 * 2048;

  int srowK = l4, skbK = l16;          // K tile: 4 rows (256B) per segment, 16 chunks/row
  int srowV = lane >> 3, skbV = lane & 7;  // V tile: 8 rows (128B) per segment, 8 chunks/row

  int nt = qt + 1;  // causal
  for (int t = 0; t < nt; ++t) {
    __syncthreads();
#pragma unroll
    for (int ii = 0; ii < 4; ++ii) {
      int s = w * 4 + ii;
      int rowK = s * 4 + srowK;
      int srcK = skbK ^ (rowK & 15);
      gload_lds16(Kbase + (size_t)(t * 64 + rowK) * 4096 + srcK * 8, &lK[s * 512]);
      int rowV = s * 8 + srowV;
      int srcV = skbV ^ (rowV & 7);
      gload_lds16(Vbase + (size_t)rowV * 2048 + t * 64 + srcV * 8, &lV[s * 512]);
    }
    __syncthreads();

    // S = Q K^T (16x64 per wave)
    f32x4 sacc[4] = {};
#pragma unroll
    for (int kk = 0; kk < 4; ++kk) {
#pragma unroll
      for (int n4 = 0; n4 < 4; ++n4) {
        int row = n4 * 16 + l16;
        int phys = (kk * 4 + l4) ^ (row & 15);
        bf16x8 kf = *(const bf16x8*)&lK[row * 128 + phys * 8];
        sacc[n4] = __builtin_amdgcn_mfma_f32_16x16x32_bf16(qf[kk], kf, sacc[n4], 0, 0, 0);
      }
    }

    const float scale = 0.08838834764831845f;  // 1/sqrt(128)
    bool diag = (t == qt);
    float sv[4][4];
#pragma unroll
    for (int n4 = 0; n4 < 4; ++n4)
#pragma unroll
      for (int i = 0; i < 4; ++i) {
        float x = sacc[n4][i] * scale;
        if (diag) {
          int qrow = w * 16 + l4 * 4 + i;
          int kvc = n4 * 16 + l16;
          if (kvc > qrow) x = -1e30f;
        }
        sv[n4][i] = x;
      }

    // online softmax, wave-parallel (rows live across 16 lanes)
#pragma unroll
    for (int i = 0; i < 4; ++i) {
      float vm = fmaxf(fmaxf(sv[0][i], sv[1][i]), fmaxf(sv[2][i], sv[3][i]));
      vm = fmaxf(vm, __shfl_xor(vm, 1));
      vm = fmaxf(vm, __shfl_xor(vm, 2));
      vm = fmaxf(vm, __shfl_xor(vm, 4));
      vm = fmaxf(vm, __shfl_xor(vm, 8));
      float mn = fmaxf(mrun[i], vm);
      float fsc = __expf(mrun[i] - mn);
      mrun[i] = mn;
      float psum = 0.f;
#pragma unroll
      for (int n4 = 0; n4 < 4; ++n4) {
        float p = __expf(sv[n4][i] - mn);
        psum += p;
        lP[w][(l4 * 4 + i) * 72 + n4 * 16 + l16] = f2bf(p);
      }
      psum += __shfl_xor(psum, 1);
      psum += __shfl_xor(psum, 2);
      psum += __shfl_xor(psum, 4);
      psum += __shfl_xor(psum, 8);
      lsum[i] = lsum[i] * fsc + psum;
#pragma unroll
      for (int n4 = 0; n4 < 8; ++n4) oacc[n4][i] *= fsc;
    }

    // O += P V  (P from per-wave LDS as A-frags, V^T tile as B-frags)
#pragma unroll
    for (int kk = 0; kk < 2; ++kk) {
      bf16x8 pf = *(const bf16x8*)&lP[w][l16 * 72 + kk * 32 + l4 * 8];
#pragma unroll
      for (int n4 = 0; n4 < 8; ++n4) {
        int d = n4 * 16 + l16;
        int phys = (kk * 4 + l4) ^ (d & 7);
        bf16x8 vf = *(const bf16x8*)&lV[d * 64 + phys * 8];
        oacc[n4] = __builtin_amdgcn_mfma_f32_16x16x32_bf16(pf, vf, oacc[n4], 0, 0, 0);
      }
    }
  }

  // epilogue: O /= lsum, store bf16 token-major
#pragma unroll
  for (int i = 0; i < 4; ++i) {
    float r = 1.0f / lsum[i];
    int tok = b * 2048 + qt * 64 + w * 16 + l4 * 4 + i;
#pragma unroll
    for (int n4 = 0; n4 < 8; ++n4)
      AO[(size_t)tok * 4096 + h * 128 + n4 * 16 + l16] = f2bf(oacc[n4][i] * r);
  }
}

// ---------- host ----------
extern "C" void kernel_launch(void* const* d_in, const int* in_sizes, int n_in,
                              void* d_out, int out_size, void* d_ws, size_t ws_size,
                              hipStream_t stream) {
  const float* X = (const float*)d_in[0];
  // d_in[1] = attention_mask (known causal; handled analytically)
  const float* Wq = (const float*)d_in[2];
  const float* Wk = (const float*)d_in[3];
  const float* Wv = (const float*)d_in[4];
  const float* Wo = (const float*)d_in[5];

  char* ws = (char*)d_ws;
  const size_t SEG = 32ull << 20;  // 32 MiB per bf16 [4096][4096]
  short* Xb  = (short*)(ws + 0 * SEG);  // later reused as AO
  short* Wqb = (short*)(ws + 1 * SEG);  // later reused as Vt
  short* Wkb = (short*)(ws + 2 * SEG);  // later reused as Wob
  short* Wvb = (short*)(ws + 3 * SEG);
  short* Qb  = (short*)(ws + 4 * SEG);
  short* Kb  = (short*)(ws + 5 * SEG);
  float2* tab = (float2*)(ws + 6 * SEG);  // 1 MiB

  const int NE = 4096 * 4096;
  cvt_bf16<<<2048, 256, 0, stream>>>(X, Xb, NE);
  cvt_bf16<<<2048, 256, 0, stream>>>(Wq, Wqb, NE);
  cvt_bf16<<<2048, 256, 0, stream>>>(Wk, Wkb, NE);
  cvt_bf16<<<2048, 256, 0, stream>>>(Wv, Wvb, NE);
  rope_table_k<<<512, 256, 0, stream>>>(tab);

  gemm128<0><<<1024, 256, 0, stream>>>(Xb, Wqb, Qb);
  gemm128<0><<<1024, 256, 0, stream>>>(Xb, Wkb, Kb);
  short* Vtb = Wqb;  // Wqb dead after Q-GEMM
  gemm128<2><<<1024, 256, 0, stream>>>(Xb, Wvb, Vtb);

  rope_apply_k<<<dim3(4096, 2), 256, 0, stream>>>(Qb, Kb, tab);

  short* AO = Xb;  // Xb dead after V-GEMM
  attn_k<<<dim3(32, 64), 256, 0, stream>>>(Qb, Kb, Vtb, AO);

  short* Wob = Wkb;  // Wkb dead after K-GEMM
  cvt_bf16<<<2048, 256, 0, stream>>>(Wo, Wob, NE);
  gemm128<1><<<1024, 256, 0, stream>>>(AO, Wob, (float*)d_out);
}

// Round 2
// 1028.348 us; speedup vs baseline: 1.1212x; 1.1212x over previous
//
#include <hip/hip_runtime.h>
#include <stdint.h>

// ---------- types ----------
typedef __attribute__((ext_vector_type(4))) float f32x4;
typedef __attribute__((ext_vector_type(8))) short bf16x8;
typedef __attribute__((ext_vector_type(4))) unsigned int u32x4;

__device__ __forceinline__ short f2bf(float x) {
  unsigned int u = __builtin_bit_cast(unsigned int, x);
  unsigned int r = (u + 0x7fffu + ((u >> 16) & 1u)) >> 16;
  return (short)r;
}
__device__ __forceinline__ float bf2f(short s) {
  unsigned int u = ((unsigned int)(unsigned short)s) << 16;
  return __builtin_bit_cast(float, u);
}
__device__ __forceinline__ unsigned pkbf(float lo, float hi) {
  unsigned r;
  asm("v_cvt_pk_bf16_f32 %0, %1, %2" : "=v"(r) : "v"(lo), "v"(hi));
  return r;
}

__device__ __forceinline__ void gload_lds16(const void* g, void* l) {
  __builtin_amdgcn_global_load_lds(
      (const __attribute__((address_space(1))) void*)g,
      (__attribute__((address_space(3))) void*)l, 16, 0, 0);
}

// ---------- K0: fp32 -> bf16 convert ----------
__global__ __launch_bounds__(256) void cvt_bf16(const float* __restrict__ in,
                                                short* __restrict__ out, int n) {
  int idx = blockIdx.x * blockDim.x + threadIdx.x;
  int stride = gridDim.x * blockDim.x;
  for (int i = idx * 4; i < n; i += stride * 4) {
    float4 v = *(const float4*)(in + i);
    short4 o;
    o.x = f2bf(v.x); o.y = f2bf(v.y); o.z = f2bf(v.z); o.w = f2bf(v.w);
    *(short4*)(out + i) = o;
  }
}

// ---------- RoPE table ----------
__global__ __launch_bounds__(256) void rope_table_k(float2* __restrict__ tab) {
  int idx = blockIdx.x * 256 + threadIdx.x;  // 131072 total
  int s = idx >> 6, j = idx & 63;
  float invf = powf(10000.0f, -((float)j) / 64.0f);
  float a = (float)s * invf;
  tab[idx] = make_float2(cosf(a), sinf(a));
}

// ---------- RoPE apply in-place on Q and K; Q additionally scaled by 1/sqrt(128) ----------
__global__ __launch_bounds__(256) void rope_apply_k(short* __restrict__ Qb,
                                                    short* __restrict__ Kb,
                                                    const float2* __restrict__ tab) {
  bool isK = (blockIdx.y != 0);
  short* base = isK ? Kb : Qb;
  float post = isK ? 1.0f : 0.08838834764831845f;  // fold 1/sqrt(HD) into Q (fp32 math)
  int token = blockIdx.x;
  int s = token & 2047;
  short* rowp = base + (size_t)token * 4096;
  const float2* trow = tab + s * 64;
  for (int u = threadIdx.x; u < 512; u += 256) {
    int h = u >> 4;
    int d0 = (u & 15) * 4;
    short* p1 = rowp + h * 128 + d0;
    short* p2 = p1 + 64;
    short4 a = *(short4*)p1, b = *(short4*)p2;
    short4 ra, rb;
#pragma unroll
    for (int j = 0; j < 4; ++j) {
      short aj = (&a.x)[j], bj = (&b.x)[j];
      float qa = bf2f(aj), qb = bf2f(bj);
      float2 cs = trow[d0 + j];
      (&ra.x)[j] = f2bf((qa * cs.x - qb * cs.y) * post);
      (&rb.x)[j] = f2bf((qb * cs.x + qa * cs.y) * post);
    }
    *(short4*)p1 = ra;
    *(short4*)p2 = rb;
  }
}

// ---------- GEMM: C[4096][4096] = A * B^T, bf16 in, fp32 acc ----------
// MODE 0: bf16 row-major out. MODE 1: fp32 row-major out. MODE 2: Vt out [bh][d][s] bf16.
template <int MODE>
__global__ __launch_bounds__(256) void gemm128(const short* __restrict__ A,
                                               const short* __restrict__ Bw,
                                               void* __restrict__ out) {
  __shared__ __attribute__((aligned(16))) short lA[128 * 64];
  __shared__ __attribute__((aligned(16))) short lB[128 * 64];
  int wg = blockIdx.x;
  int swz = (wg & 7) * 128 + (wg >> 3);
  int by = swz >> 5;
  int bx = swz & 31;
  int tid = threadIdx.x;
  int w = tid >> 6, lane = tid & 63;
  int l16 = lane & 15, l4 = lane >> 4;
  int wr = w >> 1, wc = w & 1;

  f32x4 acc[4][4] = {};

  int srow = lane >> 3;
  int skb = lane & 7;

  for (int kt = 0; kt < 64; ++kt) {
#pragma unroll
    for (int ii = 0; ii < 4; ++ii) {
      int s = w * 4 + ii;
      int row = s * 8 + srow;
      int src = skb ^ (row & 7);
      gload_lds16(A + (size_t)(by * 128 + row) * 4096 + kt * 64 + src * 8, &lA[s * 512]);
      gload_lds16(Bw + (size_t)(bx * 128 + row) * 4096 + kt * 64 + src * 8, &lB[s * 512]);
    }
    __syncthreads();
#pragma unroll
    for (int kk = 0; kk < 2; ++kk) {
      bf16x8 af[4], bfr[4];
#pragma unroll
      for (int m4 = 0; m4 < 4; ++m4) {
        int row = wr * 64 + m4 * 16 + l16;
        int phys = (kk * 4 + l4) ^ (row & 7);
        af[m4] = *(const bf16x8*)&lA[row * 64 + phys * 8];
      }
#pragma unroll
      for (int n4 = 0; n4 < 4; ++n4) {
        int row = wc * 64 + n4 * 16 + l16;
        int phys = (kk * 4 + l4) ^ (row & 7);
        bfr[n4] = *(const bf16x8*)&lB[row * 64 + phys * 8];
      }
#pragma unroll
      for (int m4 = 0; m4 < 4; ++m4)
#pragma unroll
        for (int n4 = 0; n4 < 4; ++n4)
          acc[m4][n4] = __builtin_amdgcn_mfma_f32_16x16x32_bf16(af[m4], bfr[n4], acc[m4][n4], 0, 0, 0);
    }
    __syncthreads();
  }

  int orow0 = by * 128 + wr * 64;
  int ocol0 = bx * 128 + wc * 64;
#pragma unroll
  for (int m4 = 0; m4 < 4; ++m4)
#pragma unroll
    for (int n4 = 0; n4 < 4; ++n4)
#pragma unroll
      for (int i = 0; i < 4; ++i) {
        int r = orow0 + m4 * 16 + l4 * 4 + i;
        int c = ocol0 + n4 * 16 + l16;
        float v = acc[m4][n4][i];
        if constexpr (MODE == 0) {
          ((short*)out)[(size_t)r * 4096 + c] = f2bf(v);
        } else if constexpr (MODE == 1) {
          ((float*)out)[(size_t)r * 4096 + c] = v;
        } else {
          int bb = r >> 11, ss = r & 2047;
          int h = c >> 7, d = c & 127;
          ((short*)out)[(((size_t)((bb * 32 + h) * 128 + d)) << 11) + ss] = f2bf(v);
        }
      }
}

// ---------- Flash attention v2: QBLK=128, swapped QK^T, dbuf K/V, in-register softmax ----------
// Q pre-scaled by 1/sqrt(128). Q,K token-major [4096][4096], Vt [64][128][2048], AO token-major.
__global__ __launch_bounds__(256) void attn_k(const short* __restrict__ Qb,
                                              const short* __restrict__ Kb,
                                              const short* __restrict__ Vt,
                                              short* __restrict__ AO) {
  __shared__ __attribute__((aligned(16))) short smem[2 * 16384];  // 2 x (K 16KB + V 16KB)
  int p = blockIdx.x;  // 1024 blocks: bh clustered per XCD, qt descending (LPT)
  int bh = (p & 7) + ((p >> 7) << 3);
  int qt = 15 - ((p >> 3) & 15);
  int b = bh >> 5, h = bh & 31;
  int tid = threadIdx.x, w = tid >> 6, lane = tid & 63;
  int l16 = lane & 15, l4 = lane >> 4;

  const int nt = 2 * qt + 2;
  const int qbase = qt * 128 + w * 32;  // wave owns 32 q rows

  // Q as B-frags: lane holds q-col = qbase + mg*16 + l16, d = kk*32 + l4*8 + j
  bf16x8 qf[2][4];
  {
    const short* Qg = Qb + (size_t)(b * 2048 + qbase + l16) * 4096 + h * 128 + l4 * 8;
#pragma unroll
    for (int mg = 0; mg < 2; ++mg)
#pragma unroll
      for (int kk = 0; kk < 4; ++kk)
        qf[mg][kk] = *(const bf16x8*)(Qg + (size_t)mg * 16 * 4096 + kk * 32);
  }

  f32x4 oacc[2][8] = {};  // O^T: row d = dg*16 + l4*4 + i, col q = mg*16 + l16
  float mrun[2] = {-1e30f, -1e30f}, lsum[2] = {0.f, 0.f};

  const short* Kbase = Kb + (size_t)(b * 2048) * 4096 + h * 128;
  const short* Vbase = Vt + (size_t)bh * 128 * 2048;

  const int srowK = l4, skbK = l16;
  const int srowV = lane >> 3, skbV = lane & 7;

  auto STAGE = [&](int t, int sel) {
    short* lK = &smem[sel * 16384];
    short* lV = lK + 8192;
#pragma unroll
    for (int ii = 0; ii < 4; ++ii) {
      int s = w * 4 + ii;
      int rowK = s * 4 + srowK;
      int srcK = skbK ^ (rowK & 15);
      gload_lds16(Kbase + (size_t)(t * 64 + rowK) * 4096 + srcK * 8, &lK[s * 512]);
      int rowV = s * 8 + srowV;
      int srcV = skbV ^ (rowV & 7);
      gload_lds16(Vbase + (size_t)rowV * 2048 + t * 64 + srcV * 8, &lV[s * 512]);
    }
  };

  STAGE(0, 0);
  __syncthreads();

  const int src0 = l16 | ((2 * (l4 & 1)) << 4);
  const int src1 = src0 | 16;
  const bool hiA = (l4 >> 1) != 0;

  for (int t = 0; t < nt; ++t) {
    int sel = t & 1;
    if (t + 1 < nt) STAGE(t + 1, sel ^ 1);  // prefetch next tile into other buffer
    const short* lK = &smem[sel * 16384];
    const short* lV = lK + 8192;

    bool full_skip = (t == nt - 1) && (w < 2);  // last tile fully above diagonal for waves 0,1
    if (!full_skip) {
      // S^T = K * Q^T : sacc[mg][n4], kv_loc = n4*16 + l4*4 + i, q = mg*16 + l16
      f32x4 sacc[2][4] = {};
#pragma unroll
      for (int kk = 0; kk < 4; ++kk) {
#pragma unroll
        for (int n4 = 0; n4 < 4; ++n4) {
          int row = n4 * 16 + l16;
          int phys = (kk * 4 + l4) ^ (row & 15);
          bf16x8 kf = *(const bf16x8*)&lK[row * 128 + phys * 8];
          sacc[0][n4] = __builtin_amdgcn_mfma_f32_16x16x32_bf16(kf, qf[0][kk], sacc[0][n4], 0, 0, 0);
          sacc[1][n4] = __builtin_amdgcn_mfma_f32_16x16x32_bf16(kf, qf[1][kk], sacc[1][n4], 0, 0, 0);
        }
      }

      if (t >= nt - 2) {  // diagonal zone: causal mask
#pragma unroll
        for (int mg = 0; mg < 2; ++mg) {
          int q = qbase + mg * 16 + l16;
#pragma unroll
          for (int n4 = 0; n4 < 4; ++n4)
#pragma unroll
            for (int i = 0; i < 4; ++i) {
              int kv = t * 64 + n4 * 16 + l4 * 4 + i;
              if (kv > q) sacc[mg][n4][i] = -1e30f;
            }
        }
      }

      // online softmax (q lane-local; reduce over kv: 15 in-lane + 2 shfls)
#pragma unroll
      for (int mg = 0; mg < 2; ++mg) {
        float v0 = fmaxf(fmaxf(sacc[mg][0][0], sacc[mg][0][1]), fmaxf(sacc[mg][0][2], sacc[mg][0][3]));
        float v1 = fmaxf(fmaxf(sacc[mg][1][0], sacc[mg][1][1]), fmaxf(sacc[mg][1][2], sacc[mg][1][3]));
        float v2 = fmaxf(fmaxf(sacc[mg][2][0], sacc[mg][2][1]), fmaxf(sacc[mg][2][2], sacc[mg][2][3]));
        float v3 = fmaxf(fmaxf(sacc[mg][3][0], sacc[mg][3][1]), fmaxf(sacc[mg][3][2], sacc[mg][3][3]));
        float vm = fmaxf(fmaxf(v0, v1), fmaxf(v2, v3));
        vm = fmaxf(vm, __shfl_xor(vm, 16));
        vm = fmaxf(vm, __shfl_xor(vm, 32));
        float mn = fmaxf(mrun[mg], vm);
        float fsc = __expf(mrun[mg] - mn);
        mrun[mg] = mn;
        float psum = 0.f;
#pragma unroll
        for (int n4 = 0; n4 < 4; ++n4)
#pragma unroll
          for (int i = 0; i < 4; ++i) {
            float e = __expf(sacc[mg][n4][i] - mn);
            sacc[mg][n4][i] = e;
            psum += e;
          }
        psum += __shfl_xor(psum, 16);
        psum += __shfl_xor(psum, 32);
        lsum[mg] = lsum[mg] * fsc + psum;
#pragma unroll
        for (int dg = 0; dg < 8; ++dg) oacc[mg][dg] *= fsc;
      }

      // redistribute P^T into PV B-frags: pb[mg][c][j] = P^T[c*32 + l4*8 + j][q own]
      bf16x8 pb[2][2];
#pragma unroll
      for (int mg = 0; mg < 2; ++mg)
#pragma unroll
        for (int c = 0; c < 2; ++c) {
          unsigned pk0h0 = pkbf(sacc[mg][2 * c][0], sacc[mg][2 * c][1]);
          unsigned pk0h1 = pkbf(sacc[mg][2 * c][2], sacc[mg][2 * c][3]);
          unsigned pk1h0 = pkbf(sacc[mg][2 * c + 1][0], sacc[mg][2 * c + 1][1]);
          unsigned pk1h1 = pkbf(sacc[mg][2 * c + 1][2], sacc[mg][2 * c + 1][3]);
          unsigned s00 = __shfl((int)pk0h0, src0), s10 = __shfl((int)pk1h0, src0);
          unsigned s01 = __shfl((int)pk0h1, src0), s11 = __shfl((int)pk1h1, src0);
          unsigned t00 = __shfl((int)pk0h0, src1), t10 = __shfl((int)pk1h0, src1);
          unsigned t01 = __shfl((int)pk0h1, src1), t11 = __shfl((int)pk1h1, src1);
          u32x4 uw;
          uw[0] = hiA ? s10 : s00;
          uw[1] = hiA ? s11 : s01;
          uw[2] = hiA ? t10 : t00;
          uw[3] = hiA ? t11 : t01;
          pb[mg][c] = __builtin_bit_cast(bf16x8, uw);
        }

      // O^T += V^T * P^T
#pragma unroll
      for (int c = 0; c < 2; ++c)
#pragma unroll
        for (int dg = 0; dg < 8; ++dg) {
          int d = dg * 16 + l16;
          int phys = (c * 4 + l4) ^ (d & 7);
          bf16x8 vf = *(const bf16x8*)&lV[d * 64 + phys * 8];
          oacc[0][dg] = __builtin_amdgcn_mfma_f32_16x16x32_bf16(vf, pb[0][c], oacc[0][dg], 0, 0, 0);
          oacc[1][dg] = __builtin_amdgcn_mfma_f32_16x16x32_bf16(vf, pb[1][c], oacc[1][dg], 0, 0, 0);
        }
    }
    __syncthreads();  // drains prefetch (vmcnt) + protects buffer about to be overwritten
  }

  // epilogue: normalize, transpose O^T -> O via per-wave LDS region, coalesced store
  short* reg = &smem[w * 4096];
  float rls0 = 1.0f / lsum[0], rls1 = 1.0f / lsum[1];
#pragma unroll
  for (int mg = 0; mg < 2; ++mg) {
    float rls = mg ? rls1 : rls0;
    int qloc = mg * 16 + l16;
#pragma unroll
    for (int dg = 0; dg < 8; ++dg) {
      unsigned u0 = pkbf(oacc[mg][dg][0] * rls, oacc[mg][dg][1] * rls);
      unsigned u1 = pkbf(oacc[mg][dg][2] * rls, oacc[mg][dg][3] * rls);
      int c16 = dg * 2 + (l4 >> 1);
      int phys = c16 ^ (qloc & 7);
      int sidx = qloc * 128 + phys * 8 + (l4 & 1) * 4;
      *(uint2*)&reg[sidx] = make_uint2(u0, u1);
    }
  }
#pragma unroll
  for (int pass = 0; pass < 8; ++pass) {
    int qloc = pass * 4 + l4;
    int phys = l16 ^ (qloc & 7);
    bf16x8 v = *(const bf16x8*)&reg[qloc * 128 + phys * 8];
    int qg = qt * 128 + w * 32 + qloc;
    *(bf16x8*)(AO + (size_t)(b * 2048 + qg) * 4096 + h * 128 + l16 * 8) = v;
  }
}

// ---------- host ----------
extern "C" void kernel_launch(void* const* d_in, const int* in_sizes, int n_in,
                              void* d_out, int out_size, void* d_ws, size_t ws_size,
                              hipStream_t stream) {
  const float* X = (const float*)d_in[0];
  const float* Wq = (const float*)d_in[2];
  const float* Wk = (const float*)d_in[3];
  const float* Wv = (const float*)d_in[4];
  const float* Wo = (const float*)d_in[5];

  char* ws = (char*)d_ws;
  const size_t SEG = 32ull << 20;
  short* Xb  = (short*)(ws + 0 * SEG);
  short* Wqb = (short*)(ws + 1 * SEG);
  short* Wkb = (short*)(ws + 2 * SEG);
  short* Wvb = (short*)(ws + 3 * SEG);
  short* Qb  = (short*)(ws + 4 * SEG);
  short* Kb  = (short*)(ws + 5 * SEG);
  float2* tab = (float2*)(ws + 6 * SEG);

  const int NE = 4096 * 4096;
  cvt_bf16<<<2048, 256, 0, stream>>>(X, Xb, NE);
  cvt_bf16<<<2048, 256, 0, stream>>>(Wq, Wqb, NE);
  cvt_bf16<<<2048, 256, 0, stream>>>(Wk, Wkb, NE);
  cvt_bf16<<<2048, 256, 0, stream>>>(Wv, Wvb, NE);
  rope_table_k<<<512, 256, 0, stream>>>(tab);

  gemm128<0><<<1024, 256, 0, stream>>>(Xb, Wqb, Qb);
  gemm128<0><<<1024, 256, 0, stream>>>(Xb, Wkb, Kb);
  short* Vtb = Wqb;
  gemm128<2><<<1024, 256, 0, stream>>>(Xb, Wvb, Vtb);

  rope_apply_k<<<dim3(4096, 2), 256, 0, stream>>>(Qb, Kb, tab);

  short* AO = Xb;
  attn_k<<<1024, 256, 0, stream>>>(Qb, Kb, Vtb, AO);

  short* Wob = Wkb;
  cvt_bf16<<<2048, 256, 0, stream>>>(Wo, Wob, NE);
  gemm128<1><<<1024, 256, 0, stream>>>(AO, Wob, (float*)d_out);
}

// Round 3
// 751.443 us; speedup vs baseline: 1.5344x; 1.3685x over previous
//
#include <hip/hip_runtime.h>
#include <stdint.h>

// ---------- types ----------
typedef __attribute__((ext_vector_type(4))) float f32x4;
typedef __attribute__((ext_vector_type(8))) short bf16x8;
typedef __attribute__((ext_vector_type(4))) unsigned int u32x4;

__device__ __forceinline__ short f2bf(float x) {
  unsigned int u = __builtin_bit_cast(unsigned int, x);
  unsigned int r = (u + 0x7fffu + ((u >> 16) & 1u)) >> 16;
  return (short)r;
}
__device__ __forceinline__ float bf2f(short s) {
  unsigned int u = ((unsigned int)(unsigned short)s) << 16;
  return __builtin_bit_cast(float, u);
}
__device__ __forceinline__ unsigned pkbf(float lo, float hi) {
  unsigned r;
  asm("v_cvt_pk_bf16_f32 %0, %1, %2" : "=v"(r) : "v"(lo), "v"(hi));
  return r;
}

__device__ __forceinline__ void gload_lds16(const void* g, void* l) {
  __builtin_amdgcn_global_load_lds(
      (const __attribute__((address_space(1))) void*)g,
      (__attribute__((address_space(3))) void*)l, 16, 0, 0);
}

// ---------- K0: fp32 -> bf16 convert ----------
__global__ __launch_bounds__(256) void cvt_bf16(const float* __restrict__ in,
                                                short* __restrict__ out, int n) {
  int idx = blockIdx.x * blockDim.x + threadIdx.x;
  int stride = gridDim.x * blockDim.x;
  for (int i = idx * 4; i < n; i += stride * 4) {
    float4 v = *(const float4*)(in + i);
    short4 o;
    o.x = f2bf(v.x); o.y = f2bf(v.y); o.z = f2bf(v.z); o.w = f2bf(v.w);
    *(short4*)(out + i) = o;
  }
}

// ---------- RoPE table ----------
__global__ __launch_bounds__(256) void rope_table_k(float2* __restrict__ tab) {
  int idx = blockIdx.x * 256 + threadIdx.x;  // 131072 total
  int s = idx >> 6, j = idx & 63;
  float invf = powf(10000.0f, -((float)j) / 64.0f);
  float a = (float)s * invf;
  tab[idx] = make_float2(cosf(a), sinf(a));
}

// ---------- RoPE apply in-place; Q scaled by log2(e)/sqrt(128) (log2-domain softmax) ----------
__global__ __launch_bounds__(256) void rope_apply_k(short* __restrict__ Qb,
                                                    short* __restrict__ Kb,
                                                    const float2* __restrict__ tab) {
  bool isK = (blockIdx.y != 0);
  short* base = isK ? Kb : Qb;
  float post = isK ? 1.0f : (0.08838834764831845f * 1.4426950408889634f);
  int token = blockIdx.x;
  int s = token & 2047;
  short* rowp = base + (size_t)token * 4096;
  const float2* trow = tab + s * 64;
  for (int u = threadIdx.x; u < 512; u += 256) {
    int h = u >> 4;
    int d0 = (u & 15) * 4;
    short* p1 = rowp + h * 128 + d0;
    short* p2 = p1 + 64;
    short4 a = *(short4*)p1, b = *(short4*)p2;
    short4 ra, rb;
#pragma unroll
    for (int j = 0; j < 4; ++j) {
      short aj = (&a.x)[j], bj = (&b.x)[j];
      float qa = bf2f(aj), qb = bf2f(bj);
      float2 cs = trow[d0 + j];
      (&ra.x)[j] = f2bf((qa * cs.x - qb * cs.y) * post);
      (&rb.x)[j] = f2bf((qb * cs.x + qa * cs.y) * post);
    }
    *(short4*)p1 = ra;
    *(short4*)p2 = rb;
  }
}

// ---------- GEMM 256x256 tile, BK=32, 3-buffer ring, counted vmcnt ----------
// C[4096][4096] = A * B^T. MODE 0: bf16 out. MODE 1: fp32 out. MODE 2: Vt [bh][d][s] bf16.
template <int MODE>
__global__ __launch_bounds__(512) void gemm256(const short* __restrict__ A,
                                               const short* __restrict__ Bw,
                                               void* __restrict__ out) {
  __shared__ __attribute__((aligned(16))) short smem[3 * 16384];  // 3 x (A 16KB + B 16KB)
  int wg = blockIdx.x;           // 256 blocks = 1 per CU
  int xcd = wg & 7, i = wg >> 3;
  int by = xcd * 2 + (i >> 4);   // each XCD owns 2 row-bands (A-panel L2 reuse)
  int bx = i & 15;
  int tid = threadIdx.x;
  int w = tid >> 6, lane = tid & 63;
  int l16 = lane & 15, l4 = lane >> 4;
  int wm = w >> 2, wn = w & 3;

  f32x4 acc[8][4] = {};

  const short* Ab = A + (size_t)(by * 256) * 4096;
  const short* Bb = Bw + (size_t)(bx * 256) * 4096;
  // staging: idx = j*512 + tid -> LDS chunk idx (linear), global chunk (idx&3)^(row&3)
  int idx0 = tid, idx1 = 512 + tid;
  int r0 = idx0 >> 2, c0l = (idx0 & 3) ^ (r0 & 3);
  int r1 = idx1 >> 2, c1l = (idx1 & 3) ^ (r1 & 3);
  int db0 = (0 * 512 + w * 64) * 8;  // wave-uniform LDS dest bases (shorts)
  int db1 = (1 * 512 + w * 64) * 8;

  auto STAGE = [&](int kt, int ob) {
    gload_lds16(Ab + (size_t)r0 * 4096 + kt * 32 + c0l * 8, &smem[ob + db0]);
    gload_lds16(Ab + (size_t)r1 * 4096 + kt * 32 + c1l * 8, &smem[ob + db1]);
    gload_lds16(Bb + (size_t)r0 * 4096 + kt * 32 + c0l * 8, &smem[ob + 8192 + db0]);
    gload_lds16(Bb + (size_t)r1 * 4096 + kt * 32 + c1l * 8, &smem[ob + 8192 + db1]);
  };

  int o0 = 0, o1 = 16384, o2 = 32768;
  STAGE(0, o0);
  STAGE(1, o1);

  const int physc = l4 ^ (l16 & 3);
  const int arow = wm * 128 + l16;
  const int brow = wn * 64 + l16;

  auto COMPUTE = [&](int ob) {
    const short* lA = &smem[ob];
    const short* lB = &smem[ob + 8192];
    bf16x8 af[4], bfr[4];
#pragma unroll
    for (int nf = 0; nf < 4; ++nf)
      bfr[nf] = *(const bf16x8*)&lB[(brow + nf * 16) * 32 + physc * 8];
#pragma unroll
    for (int mf = 0; mf < 4; ++mf)
      af[mf] = *(const bf16x8*)&lA[(arow + mf * 16) * 32 + physc * 8];
    __builtin_amdgcn_s_setprio(1);
#pragma unroll
    for (int mf = 0; mf < 4; ++mf)
#pragma unroll
      for (int nf = 0; nf < 4; ++nf)
        acc[mf][nf] = __builtin_amdgcn_mfma_f32_16x16x32_bf16(af[mf], bfr[nf], acc[mf][nf], 0, 0, 0);
    __builtin_amdgcn_s_setprio(0);
#pragma unroll
    for (int mf = 0; mf < 4; ++mf)
      af[mf] = *(const bf16x8*)&lA[(arow + 64 + mf * 16) * 32 + physc * 8];
    __builtin_amdgcn_s_setprio(1);
#pragma unroll
    for (int mf = 0; mf < 4; ++mf)
#pragma unroll
      for (int nf = 0; nf < 4; ++nf)
        acc[mf + 4][nf] = __builtin_amdgcn_mfma_f32_16x16x32_bf16(af[mf], bfr[nf], acc[mf + 4][nf], 0, 0, 0);
    __builtin_amdgcn_s_setprio(0);
  };

  for (int t = 0; t < 127; ++t) {
    asm volatile("s_waitcnt vmcnt(4)" ::: "memory");  // tile t resident (t+1 may fly)
    __builtin_amdgcn_s_barrier();                     // all threads' t-loads done; reads of t-1 done
    asm volatile("" ::: "memory");
    if (t + 2 < 128) STAGE(t + 2, o2);                // dest buffer idle (last read at t-1)
    COMPUTE(o0);
    int tmp = o0; o0 = o1; o1 = o2; o2 = tmp;
  }
  asm volatile("s_waitcnt vmcnt(0)" ::: "memory");
  __builtin_amdgcn_s_barrier();
  asm volatile("" ::: "memory");
  COMPUTE(o0);

  int orow0 = by * 256 + wm * 128;
  int ocol0 = bx * 256 + wn * 64;
#pragma unroll
  for (int mf = 0; mf < 8; ++mf)
#pragma unroll
    for (int nf = 0; nf < 4; ++nf)
#pragma unroll
      for (int ii = 0; ii < 4; ++ii) {
        int r = orow0 + mf * 16 + l4 * 4 + ii;
        int c = ocol0 + nf * 16 + l16;
        float v = acc[mf][nf][ii];
        if constexpr (MODE == 0) {
          ((short*)out)[(size_t)r * 4096 + c] = f2bf(v);
        } else if constexpr (MODE == 1) {
          ((float*)out)[(size_t)r * 4096 + c] = v;
        } else {
          int bb = r >> 11, ss = r & 2047;
          int h = c >> 7, d = c & 127;
          ((short*)out)[(((size_t)((bb * 32 + h) * 128 + d)) << 11) + ss] = f2bf(v);
        }
      }
}

// ---------- Flash attention: QBLK=128, swapped QK^T, dbuf K/V, log2-domain softmax, defer-max ----------
// Q pre-scaled by log2e/sqrt(128). Q,K token-major [4096][4096], Vt [64][128][2048], AO token-major.
__global__ __launch_bounds__(256) void attn_k(const short* __restrict__ Qb,
                                              const short* __restrict__ Kb,
                                              const short* __restrict__ Vt,
                                              short* __restrict__ AO) {
  __shared__ __attribute__((aligned(16))) short smem[2 * 16384];  // 2 x (K 16KB + V 16KB)
  int p = blockIdx.x;  // qt-major (LPT): longest blocks dispatch first
  int bh = p & 63;
  int qt = 15 - (p >> 6);
  int b = bh >> 5, h = bh & 31;
  int tid = threadIdx.x, w = tid >> 6, lane = tid & 63;
  int l16 = lane & 15, l4 = lane >> 4;

  const int nt = 2 * qt + 2;
  const int qbase = qt * 128 + w * 32;

  bf16x8 qf[2][4];
  {
    const short* Qg = Qb + (size_t)(b * 2048 + qbase + l16) * 4096 + h * 128 + l4 * 8;
#pragma unroll
    for (int mg = 0; mg < 2; ++mg)
#pragma unroll
      for (int kk = 0; kk < 4; ++kk)
        qf[mg][kk] = *(const bf16x8*)(Qg + (size_t)mg * 16 * 4096 + kk * 32);
  }

  f32x4 oacc[2][8] = {};
  float mrun[2] = {-1e30f, -1e30f}, lsum[2] = {0.f, 0.f};

  const short* Kbase = Kb + (size_t)(b * 2048) * 4096 + h * 128;
  const short* Vbase = Vt + (size_t)bh * 128 * 2048;

  const int srowK = l4, skbK = l16;
  const int srowV = lane >> 3, skbV = lane & 7;

  auto STAGE = [&](int t, int sel) {
    short* lK = &smem[sel * 16384];
    short* lV = lK + 8192;
#pragma unroll
    for (int ii = 0; ii < 4; ++ii) {
      int s = w * 4 + ii;
      int rowK = s * 4 + srowK;
      int srcK = skbK ^ (rowK & 15);
      gload_lds16(Kbase + (size_t)(t * 64 + rowK) * 4096 + srcK * 8, &lK[s * 512]);
      int rowV = s * 8 + srowV;
      int srcV = skbV ^ (rowV & 7);
      gload_lds16(Vbase + (size_t)rowV * 2048 + t * 64 + srcV * 8, &lV[s * 512]);
    }
  };

  STAGE(0, 0);
  __syncthreads();

  const int src0 = l16 | ((2 * (l4 & 1)) << 4);
  const int src1 = src0 | 16;
  const bool hiA = (l4 >> 1) != 0;

  for (int t = 0; t < nt; ++t) {
    int sel = t & 1;
    if (t + 1 < nt) STAGE(t + 1, sel ^ 1);
    const short* lK = &smem[sel * 16384];
    const short* lV = lK + 8192;

    bool full_skip = (t == nt - 1) && (w < 2);
    if (!full_skip) {
      f32x4 sacc[2][4] = {};
#pragma unroll
      for (int kk = 0; kk < 4; ++kk) {
#pragma unroll
        for (int n4 = 0; n4 < 4; ++n4) {
          int row = n4 * 16 + l16;
          int phys = (kk * 4 + l4) ^ (row & 15);
          bf16x8 kf = *(const bf16x8*)&lK[row * 128 + phys * 8];
          sacc[0][n4] = __builtin_amdgcn_mfma_f32_16x16x32_bf16(kf, qf[0][kk], sacc[0][n4], 0, 0, 0);
          sacc[1][n4] = __builtin_amdgcn_mfma_f32_16x16x32_bf16(kf, qf[1][kk], sacc[1][n4], 0, 0, 0);
        }
      }

      if (t >= nt - 2) {
#pragma unroll
        for (int mg = 0; mg < 2; ++mg) {
          int q = qbase + mg * 16 + l16;
#pragma unroll
          for (int n4 = 0; n4 < 4; ++n4)
#pragma unroll
            for (int i = 0; i < 4; ++i) {
              int kv = t * 64 + n4 * 16 + l4 * 4 + i;
              if (kv > q) sacc[mg][n4][i] = -1e30f;
            }
        }
      }

      // online softmax in log2 domain, defer-max (THR=8 -> P <= 256)
#pragma unroll
      for (int mg = 0; mg < 2; ++mg) {
        float v0 = fmaxf(fmaxf(sacc[mg][0][0], sacc[mg][0][1]), fmaxf(sacc[mg][0][2], sacc[mg][0][3]));
        float v1 = fmaxf(fmaxf(sacc[mg][1][0], sacc[mg][1][1]), fmaxf(sacc[mg][1][2], sacc[mg][1][3]));
        float v2 = fmaxf(fmaxf(sacc[mg][2][0], sacc[mg][2][1]), fmaxf(sacc[mg][2][2], sacc[mg][2][3]));
        float v3 = fmaxf(fmaxf(sacc[mg][3][0], sacc[mg][3][1]), fmaxf(sacc[mg][3][2], sacc[mg][3][3]));
        float vm = fmaxf(fmaxf(v0, v1), fmaxf(v2, v3));
        vm = fmaxf(vm, __shfl_xor(vm, 16));
        vm = fmaxf(vm, __shfl_xor(vm, 32));
        float mn = mrun[mg];
        if (!__all(vm - mn <= 8.0f)) {
          float mnew = fmaxf(mn, vm);
          float fsc = __builtin_amdgcn_exp2f(mn - mnew);
          mrun[mg] = mnew;
          lsum[mg] *= fsc;
#pragma unroll
          for (int dg = 0; dg < 8; ++dg) oacc[mg][dg] *= fsc;
          mn = mnew;
        }
        float psum = 0.f;
#pragma unroll
        for (int n4 = 0; n4 < 4; ++n4)
#pragma unroll
          for (int i = 0; i < 4; ++i) {
            float e = __builtin_amdgcn_exp2f(sacc[mg][n4][i] - mn);
            sacc[mg][n4][i] = e;
            psum += e;
          }
        psum += __shfl_xor(psum, 16);
        psum += __shfl_xor(psum, 32);
        lsum[mg] += psum;
      }

      bf16x8 pb[2][2];
#pragma unroll
      for (int mg = 0; mg < 2; ++mg)
#pragma unroll
        for (int c = 0; c < 2; ++c) {
          unsigned pk0h0 = pkbf(sacc[mg][2 * c][0], sacc[mg][2 * c][1]);
          unsigned pk0h1 = pkbf(sacc[mg][2 * c][2], sacc[mg][2 * c][3]);
          unsigned pk1h0 = pkbf(sacc[mg][2 * c + 1][0], sacc[mg][2 * c + 1][1]);
          unsigned pk1h1 = pkbf(sacc[mg][2 * c + 1][2], sacc[mg][2 * c + 1][3]);
          unsigned s00 = __shfl((int)pk0h0, src0), s10 = __shfl((int)pk1h0, src0);
          unsigned s01 = __shfl((int)pk0h1, src0), s11 = __shfl((int)pk1h1, src0);
          unsigned t00 = __shfl((int)pk0h0, src1), t10 = __shfl((int)pk1h0, src1);
          unsigned t01 = __shfl((int)pk0h1, src1), t11 = __shfl((int)pk1h1, src1);
          u32x4 uw;
          uw[0] = hiA ? s10 : s00;
          uw[1] = hiA ? s11 : s01;
          uw[2] = hiA ? t10 : t00;
          uw[3] = hiA ? t11 : t01;
          pb[mg][c] = __builtin_bit_cast(bf16x8, uw);
        }

#pragma unroll
      for (int c = 0; c < 2; ++c)
#pragma unroll
        for (int dg = 0; dg < 8; ++dg) {
          int d = dg * 16 + l16;
          int phys = (c * 4 + l4) ^ (d & 7);
          bf16x8 vf = *(const bf16x8*)&lV[d * 64 + phys * 8];
          oacc[0][dg] = __builtin_amdgcn_mfma_f32_16x16x32_bf16(vf, pb[0][c], oacc[0][dg], 0, 0, 0);
          oacc[1][dg] = __builtin_amdgcn_mfma_f32_16x16x32_bf16(vf, pb[1][c], oacc[1][dg], 0, 0, 0);
        }
    }
    __syncthreads();
  }

  short* reg = &smem[w * 4096];
  float rls0 = 1.0f / lsum[0], rls1 = 1.0f / lsum[1];
#pragma unroll
  for (int mg = 0; mg < 2; ++mg) {
    float rls = mg ? rls1 : rls0;
    int qloc = mg * 16 + l16;
#pragma unroll
    for (int dg = 0; dg < 8; ++dg) {
      unsigned u0 = pkbf(oacc[mg][dg][0] * rls, oacc[mg][dg][1] * rls);
      unsigned u1 = pkbf(oacc[mg][dg][2] * rls, oacc[mg][dg][3] * rls);
      int c16 = dg * 2 + (l4 >> 1);
      int phys = c16 ^ (qloc & 7);
      int sidx = qloc * 128 + phys * 8 + (l4 & 1) * 4;
      *(uint2*)&reg[sidx] = make_uint2(u0, u1);
    }
  }
#pragma unroll
  for (int pass = 0; pass < 8; ++pass) {
    int qloc = pass * 4 + l4;
    int phys = l16 ^ (qloc & 7);
    bf16x8 v = *(const bf16x8*)&reg[qloc * 128 + phys * 8];
    int qg = qt * 128 + w * 32 + qloc;
    *(bf16x8*)(AO + (size_t)(b * 2048 + qg) * 4096 + h * 128 + l16 * 8) = v;
  }
}

// ---------- host ----------
extern "C" void kernel_launch(void* const* d_in, const int* in_sizes, int n_in,
                              void* d_out, int out_size, void* d_ws, size_t ws_size,
                              hipStream_t stream) {
  const float* X = (const float*)d_in[0];
  const float* Wq = (const float*)d_in[2];
  const float* Wk = (const float*)d_in[3];
  const float* Wv = (const float*)d_in[4];
  const float* Wo = (const float*)d_in[5];

  char* ws = (char*)d_ws;
  const size_t SEG = 32ull << 20;
  short* Xb  = (short*)(ws + 0 * SEG);
  short* Wqb = (short*)(ws + 1 * SEG);
  short* Wkb = (short*)(ws + 2 * SEG);
  short* Wvb = (short*)(ws + 3 * SEG);
  short* Qb  = (short*)(ws + 4 * SEG);
  short* Kb  = (short*)(ws + 5 * SEG);
  float2* tab = (float2*)(ws + 6 * SEG);

  const int NE = 4096 * 4096;
  cvt_bf16<<<2048, 256, 0, stream>>>(X, Xb, NE);
  cvt_bf16<<<2048, 256, 0, stream>>>(Wq, Wqb, NE);
  cvt_bf16<<<2048, 256, 0, stream>>>(Wk, Wkb, NE);
  cvt_bf16<<<2048, 256, 0, stream>>>(Wv, Wvb, NE);
  rope_table_k<<<512, 256, 0, stream>>>(tab);

  gemm256<0><<<256, 512, 0, stream>>>(Xb, Wqb, Qb);
  gemm256<0><<<256, 512, 0, stream>>>(Xb, Wkb, Kb);
  short* Vtb = Wqb;
  gemm256<2><<<256, 512, 0, stream>>>(Xb, Wvb, Vtb);

  rope_apply_k<<<dim3(4096, 2), 256, 0, stream>>>(Qb, Kb, tab);

  short* AO = Xb;
  attn_k<<<1024, 256, 0, stream>>>(Qb, Kb, Vtb, AO);

  short* Wob = Wkb;
  cvt_bf16<<<2048, 256, 0, stream>>>(Wo, Wob, NE);
  gemm256<1><<<256, 512, 0, stream>>>(AO, Wob, (float*)d_out);
}